// Round 11
// baseline (223.024 us; speedup 1.0000x reference)
//
#include <hip/hip_runtime.h>

typedef __bf16 bf16x8 __attribute__((ext_vector_type(8)));
typedef float f32x4 __attribute__((ext_vector_type(4)));
typedef float f32x16 __attribute__((ext_vector_type(16)));
typedef unsigned u32x4 __attribute__((ext_vector_type(4)));
typedef unsigned short u16;

#define GAS __attribute__((address_space(1)))
#define LAS __attribute__((address_space(3)))

static __device__ __forceinline__ void gload16(const void* g, void* l) {
  __builtin_amdgcn_global_load_lds((const GAS unsigned int*)g, (LAS unsigned int*)l, 16, 0, 0);
}

static __device__ __forceinline__ u16 f2bf(float f) {
  unsigned u = __builtin_bit_cast(unsigned, f);
  u += 0x7fffu + ((u >> 16) & 1u);
  return (u16)(u >> 16);
}

static __device__ __forceinline__ unsigned pk2(float lo, float hi) {
  ushort2 u;
  u.x = __builtin_bit_cast(u16, (__bf16)lo);
  u.y = __builtin_bit_cast(u16, (__bf16)hi);
  return __builtin_bit_cast(unsigned, u);
}

// ---------------- fused fp32 -> bf16 convert ----------------
__global__ void cvt_all(const float* __restrict__ x, const float* __restrict__ wq,
                        const float* __restrict__ wk, const float* __restrict__ wv,
                        const float* __restrict__ wo, u16* __restrict__ xb,
                        u16* __restrict__ wqkvb, u16* __restrict__ wob) {
  int i = blockIdx.x * 256 + threadIdx.x;
  float4 v;
  ushort4* dst;
  if (i < 2097152) {
    v = reinterpret_cast<const float4*>(x)[i];
    dst = reinterpret_cast<ushort4*>(xb) + i;
  } else if (i < 2883584) {
    int j = i - 2097152;
    const float* s = j < 262144 ? wq : (j < 524288 ? wk : wv);
    int jj = j < 262144 ? j : (j < 524288 ? j - 262144 : j - 524288);
    v = reinterpret_cast<const float4*>(s)[jj];
    dst = reinterpret_cast<ushort4*>(wqkvb) + j;
  } else {
    int j = i - 2883584;
    v = reinterpret_cast<const float4*>(wo)[j];
    dst = reinterpret_cast<ushort4*>(wob) + j;
  }
  ushort4 o;
  o.x = f2bf(v.x); o.y = f2bf(v.y); o.z = f2bf(v.z); o.w = f2bf(v.w);
  *dst = o;
}

// ---------------- QKV GEMM: C[8192x3072] = X[8192x1024] @ Wqkv^T ----------------
// Double-buffered LDS (BK=32), single barrier per K-step.
// V epilogue: kv column index with bits 2<->3 swapped so attention's 32x32 PV B-frag
// is one contiguous swizzled b128 read.
__global__ void gemm_qkv(const u16* __restrict__ A, const u16* __restrict__ W,
                         u16* __restrict__ Qo, u16* __restrict__ Ko, u16* __restrict__ Vo) {
  __shared__ u16 As[2 * 128 * 32];
  __shared__ u16 Bs[2 * 128 * 32];
  const int t = threadIdx.x;
  const int lane = t & 63;
  const int w = t >> 6;
  const int wr = w >> 1, wc = w & 1;
  const int l15 = lane & 15, lhi = lane >> 4;
  const int swz = (blockIdx.x & 7) * 192 + (blockIdx.x >> 3);
  const int bm = swz / 24, bn = swz % 24;

  f32x4 acc[4][4];
#pragma unroll
  for (int a = 0; a < 4; ++a)
#pragma unroll
    for (int b = 0; b < 4; ++b) acc[a][b] = (f32x4){0.f, 0.f, 0.f, 0.f};

  const u16* ag = A + (size_t)(bm * 128 + (t >> 2)) * 1024 + (t & 3) * 8;
  const u16* bg = W + (size_t)(bn * 128 + (t >> 2)) * 1024 + (t & 3) * 8;

  auto stage = [&](int cb, int kt) {
    gload16(ag + kt * 32, &As[cb + t * 8]);
    gload16(ag + kt * 32 + 64 * 1024, &As[cb + t * 8 + 2048]);
    gload16(bg + kt * 32, &Bs[cb + t * 8]);
    gload16(bg + kt * 32 + 64 * 1024, &Bs[cb + t * 8 + 2048]);
  };

  stage(0, 0);
  asm volatile("s_waitcnt vmcnt(0)" ::: "memory");
  __builtin_amdgcn_s_barrier();

  for (int kt = 0; kt < 32; ++kt) {
    const int cb = (kt & 1) * 4096;
    if (kt < 31) stage(cb ^ 4096, kt + 1);
    bf16x8 af[4], bfr[4];
#pragma unroll
    for (int mt = 0; mt < 4; ++mt)
      af[mt] = *(const bf16x8*)&As[cb + (wr * 64 + mt * 16 + l15) * 32 + lhi * 8];
#pragma unroll
    for (int nt = 0; nt < 4; ++nt)
      bfr[nt] = *(const bf16x8*)&Bs[cb + (wc * 64 + nt * 16 + l15) * 32 + lhi * 8];
#pragma unroll
    for (int mt = 0; mt < 4; ++mt)
#pragma unroll
      for (int nt = 0; nt < 4; ++nt)
        acc[mt][nt] = __builtin_amdgcn_mfma_f32_16x16x32_bf16(af[mt], bfr[nt], acc[mt][nt], 0, 0, 0);
    asm volatile("s_waitcnt vmcnt(0)" ::: "memory");
    __builtin_amdgcn_s_barrier();
  }

  const int tsel = bn >> 3;
  const int m0 = bm * 128 + wr * 64;
  const int n0 = bn * 128 + wc * 64;
  const int bb = bm >> 4;
  if (tsel == 0) {
    const float qs = 0.125f * 1.4426950408889634f;  // fold softmax scale + log2e
#pragma unroll
    for (int nt = 0; nt < 4; ++nt) {
      int n = n0 + nt * 16 + l15;
      int c = n & 1023, h = c >> 6, hd = c & 63;
      size_t base = (size_t)(bb * 16 + h) * 2048 * 64 + hd;
#pragma unroll
      for (int mt = 0; mt < 4; ++mt)
#pragma unroll
        for (int i = 0; i < 4; ++i) {
          int s = (m0 + mt * 16 + lhi * 4 + i) & 2047;
          Qo[base + (size_t)s * 64] = f2bf(acc[mt][nt][i] * qs);
        }
    }
  } else if (tsel == 1) {
#pragma unroll
    for (int nt = 0; nt < 4; ++nt) {
      int n = n0 + nt * 16 + l15;
      int c = n & 1023, h = c >> 6, hd = c & 63;
      size_t base = (size_t)(bb * 16 + h) * 2048 * 64 + hd;
#pragma unroll
      for (int mt = 0; mt < 4; ++mt)
#pragma unroll
        for (int i = 0; i < 4; ++i) {
          int s = (m0 + mt * 16 + lhi * 4 + i) & 2047;
          Ko[base + (size_t)s * 64] = f2bf(acc[mt][nt][i]);
        }
    }
  } else {
#pragma unroll
    for (int nt = 0; nt < 4; ++nt) {
      int n = n0 + nt * 16 + l15;
      int c = n & 1023, h = c >> 6, hd = c & 63;
#pragma unroll
      for (int mt = 0; mt < 4; ++mt) {
        int s0 = (m0 + mt * 16 + lhi * 4) & 2047;
        // swap kv bits 2 and 3 (s0 has bits 0-1 clear; i=0..3 stays contiguous)
        int p0 = (s0 & ~12) | (((s0 >> 2) & 1) << 3) | (((s0 >> 3) & 1) << 2);
        ushort4 pk;
        pk.x = f2bf(acc[mt][nt][0]);
        pk.y = f2bf(acc[mt][nt][1]);
        pk.z = f2bf(acc[mt][nt][2]);
        pk.w = f2bf(acc[mt][nt][3]);
        *(ushort4*)&Vo[((size_t)(bb * 16 + h) * 64 + hd) * 2048 + p0] = pk;
      }
    }
  }
}

// ---------------- Flash attention: 32x32x16 MFMA, 4 waves, 32 q-rows/wave, KVBLK=64 --------
// Swapped QK^T (32x32): lane holds S^T[kv][q=lane&31], 16 f32 regs per 32-kv tile;
// kv = (reg&3) + 8*(reg>>2) + 4*hi (+32*tile). PV sigma: A-slot k=8hi+j <-> kv =
// 16s+(j&3)+8*(j>>2)+4hi = lane's own regs 8(s&1)+j of tile s>>1 -- zero shuffles.
// V stored with kv bits 2<->3 swapped -> B-frag is one contiguous swizzled b128.
// Fixed-scale softmax (exp2 direct); l via mfma(P, ones); co/la share the same
// reg->q mapping so the epilogue is elementwise.
__global__ __launch_bounds__(256, 4) void attn_kernel(const u16* __restrict__ Q,
                                                      const u16* __restrict__ K,
                                                      const u16* __restrict__ Vp,
                                                      u16* __restrict__ Ctx) {
  __shared__ u16 Ks[2 * 64 * 64];  // [buf][kv][d]
  __shared__ u16 Vs[2 * 64 * 64];  // [buf][hd][kv bit-swapped]
  const int t = threadIdx.x;
  const int lane = t & 63;
  const int w = t >> 6;  // 4 waves
  const int l31 = lane & 31, hi = lane >> 5;
  const int swz = (blockIdx.x & 7) * 128 + (blockIdx.x >> 3);  // grid 1024 = 8*128
  const int qt = swz & 15, pair = swz >> 4;
  const u16* qp = Q + (size_t)pair * 2048 * 64;
  const u16* kp = K + (size_t)pair * 2048 * 64;
  const u16* vp = Vp + (size_t)pair * 64 * 2048;

  // Q B-frags: lane supplies Q[q=l31-row][d = dstep*16 + hi*8 + j]
  const int qrow = qt * 128 + w * 32 + l31;
  bf16x8 qf[4];
#pragma unroll
  for (int d = 0; d < 4; ++d)
    qf[d] = *(const bf16x8*)&qp[(size_t)qrow * 64 + d * 16 + hi * 8];

  const u32x4 ow = {0x3F803F80u, 0x3F803F80u, 0x3F803F80u, 0x3F803F80u};
  const bf16x8 onesf = __builtin_bit_cast(bf16x8, ow);

  const int swzk = (l31 & 7) << 3;
  // K col offsets per dstep (elements), kt-invariant
  int kc[4];
#pragma unroll
  for (int d = 0; d < 4; ++d) kc[d] = (d * 16 + hi * 8) ^ swzk;

  const f32x16 fz = {0.f, 0.f, 0.f, 0.f, 0.f, 0.f, 0.f, 0.f,
                     0.f, 0.f, 0.f, 0.f, 0.f, 0.f, 0.f, 0.f};
  f32x16 co0 = fz, co1 = fz, la = fz;

  auto stage = [&](int cb, int tt) {
#pragma unroll
    for (int j = 0; j < 2; ++j) {
      int c = j * 256 + t;
      int r = c >> 3, c8 = (c & 7) * 8;
      gload16(kp + (size_t)(tt * 64 + r) * 64 + (c8 ^ ((r & 7) << 3)), &Ks[cb + c * 8]);
    }
#pragma unroll
    for (int j = 0; j < 2; ++j) {
      int c = j * 256 + t;
      int r = c >> 3, c8 = (c & 7) * 8;
      gload16(vp + (size_t)r * 2048 + tt * 64 + (c8 ^ ((r & 7) << 3)), &Vs[cb + c * 8]);
    }
  };

  stage(0, 0);
  asm volatile("s_waitcnt vmcnt(0)" ::: "memory");
  __builtin_amdgcn_s_barrier();

  for (int kt = 0; kt < 32; ++kt) {
    const int cb = (kt & 1) * 4096;
    if (kt < 31) stage(cb ^ 4096, kt + 1);  // issue early; drained at loop bottom

#pragma unroll
    for (int ph = 0; ph < 2; ++ph) {  // two 32-kv tiles per staged 64-kv block
      // ---- QK^T: sa = K_tile^T-contract with Q over d (4 chained MFMAs) ----
      const int krow = cb + ph * 2048 + l31 * 64;
      f32x16 sa;
      __builtin_amdgcn_s_setprio(1);
      {
        bf16x8 kf0 = *(const bf16x8*)&Ks[krow + kc[0]];
        bf16x8 kf1 = *(const bf16x8*)&Ks[krow + kc[1]];
        bf16x8 kf2 = *(const bf16x8*)&Ks[krow + kc[2]];
        bf16x8 kf3 = *(const bf16x8*)&Ks[krow + kc[3]];
        sa = __builtin_amdgcn_mfma_f32_32x32x16_bf16(kf0, qf[0], fz, 0, 0, 0);
        sa = __builtin_amdgcn_mfma_f32_32x32x16_bf16(kf1, qf[1], sa, 0, 0, 0);
        sa = __builtin_amdgcn_mfma_f32_32x32x16_bf16(kf2, qf[2], sa, 0, 0, 0);
        sa = __builtin_amdgcn_mfma_f32_32x32x16_bf16(kf3, qf[3], sa, 0, 0, 0);
      }
      __builtin_amdgcn_s_setprio(0);

      // ---- fixed-scale softmax: exp2 direct, pack pairs of consecutive regs ----
#pragma unroll
      for (int e = 0; e < 16; ++e) sa[e] = __builtin_exp2f(sa[e]);
      unsigned pw[8];
#pragma unroll
      for (int r = 0; r < 8; ++r) pw[r] = pk2(sa[2 * r], sa[2 * r + 1]);

      // ---- PV + l-sum: 2 kv-16-groups (ss), 2 hd-tiles each ----
      __builtin_amdgcn_s_setprio(1);
#pragma unroll
      for (int ss = 0; ss < 2; ++ss) {
        u32x4 aw = {pw[4 * ss + 0], pw[4 * ss + 1], pw[4 * ss + 2], pw[4 * ss + 3]};
        bf16x8 af = __builtin_bit_cast(bf16x8, aw);
        la = __builtin_amdgcn_mfma_f32_32x32x16_bf16(af, onesf, la, 0, 0, 0);
        const int s = ph * 2 + ss;
        const int vcol = (s * 16 + hi * 8) ^ swzk;
        bf16x8 vf0 = *(const bf16x8*)&Vs[cb + l31 * 64 + vcol];
        bf16x8 vf1 = *(const bf16x8*)&Vs[cb + (32 + l31) * 64 + vcol];
        co0 = __builtin_amdgcn_mfma_f32_32x32x16_bf16(af, vf0, co0, 0, 0, 0);
        co1 = __builtin_amdgcn_mfma_f32_32x32x16_bf16(af, vf1, co1, 0, 0, 0);
      }
      __builtin_amdgcn_s_setprio(0);
    }

    asm volatile("s_waitcnt vmcnt(0)" ::: "memory");  // stage(t+1) drained (hidden)
    __builtin_amdgcn_s_barrier();                      // single barrier per kt
  }

  // ---- epilogue: out = co / la, identical reg->q mapping ----
  const int bb = pair >> 4, hh = pair & 15;
  const int qbase = qt * 128 + w * 32 + 4 * hi;
#pragma unroll
  for (int r = 0; r < 16; ++r) {
    int q = qbase + (r & 3) + 8 * (r >> 2);
    float li = 1.0f / la[r];
    size_t rowb = (size_t)(bb * 2048 + q) * 1024 + hh * 64;
    Ctx[rowb + l31] = f2bf(co0[r] * li);
    Ctx[rowb + 32 + l31] = f2bf(co1[r] * li);
  }
}

// ---------------- Output GEMM: out[8192x1024] = Ctx @ Wo^T + bo (fp32 out) ----------------
__global__ void gemm_out(const u16* __restrict__ A, const u16* __restrict__ W,
                         const float* __restrict__ Bo, float* __restrict__ Out) {
  __shared__ u16 As[2 * 128 * 32];
  __shared__ u16 Bs[2 * 128 * 32];
  const int t = threadIdx.x;
  const int lane = t & 63;
  const int w = t >> 6;
  const int wr = w >> 1, wc = w & 1;
  const int l15 = lane & 15, lhi = lane >> 4;
  const int swz = (blockIdx.x & 7) * 64 + (blockIdx.x >> 3);
  const int bm = swz >> 3, bn = swz & 7;

  f32x4 acc[4][4];
#pragma unroll
  for (int a = 0; a < 4; ++a)
#pragma unroll
    for (int b = 0; b < 4; ++b) acc[a][b] = (f32x4){0.f, 0.f, 0.f, 0.f};

  const u16* ag = A + (size_t)(bm * 128 + (t >> 2)) * 1024 + (t & 3) * 8;
  const u16* bg = W + (size_t)(bn * 128 + (t >> 2)) * 1024 + (t & 3) * 8;

  auto stage = [&](int cb, int kt) {
    gload16(ag + kt * 32, &As[cb + t * 8]);
    gload16(ag + kt * 32 + 64 * 1024, &As[cb + t * 8 + 2048]);
    gload16(bg + kt * 32, &Bs[cb + t * 8]);
    gload16(bg + kt * 32 + 64 * 1024, &Bs[cb + t * 8 + 2048]);
  };

  stage(0, 0);
  asm volatile("s_waitcnt vmcnt(0)" ::: "memory");
  __builtin_amdgcn_s_barrier();

  for (int kt = 0; kt < 32; ++kt) {
    const int cb = (kt & 1) * 4096;
    if (kt < 31) stage(cb ^ 4096, kt + 1);
    bf16x8 af[4], bfr[4];
#pragma unroll
    for (int mt = 0; mt < 4; ++mt)
      af[mt] = *(const bf16x8*)&As[cb + (wr * 64 + mt * 16 + l15) * 32 + lhi * 8];
#pragma unroll
    for (int nt = 0; nt < 4; ++nt)
      bfr[nt] = *(const bf16x8*)&Bs[cb + (wc * 64 + nt * 16 + l15) * 32 + lhi * 8];
#pragma unroll
    for (int mt = 0; mt < 4; ++mt)
#pragma unroll
      for (int nt = 0; nt < 4; ++nt)
        acc[mt][nt] = __builtin_amdgcn_mfma_f32_16x16x32_bf16(af[mt], bfr[nt], acc[mt][nt], 0, 0, 0);
    asm volatile("s_waitcnt vmcnt(0)" ::: "memory");
    __builtin_amdgcn_s_barrier();
  }

  const int m0 = bm * 128 + wr * 64;
  const int n0 = bn * 128 + wc * 64;
#pragma unroll
  for (int nt = 0; nt < 4; ++nt) {
    int n = n0 + nt * 16 + l15;
    float bias = Bo[n];
#pragma unroll
    for (int mt = 0; mt < 4; ++mt)
#pragma unroll
      for (int i = 0; i < 4; ++i) {
        int m = m0 + mt * 16 + lhi * 4 + i;
        Out[(size_t)m * 1024 + n] = acc[mt][nt][i] + bias;
      }
  }
}

// ---------------- launch ----------------
extern "C" void kernel_launch(void* const* d_in, const int* in_sizes, int n_in,
                              void* d_out, int out_size, void* d_ws, size_t ws_size,
                              hipStream_t stream) {
  const float* x  = (const float*)d_in[0];
  const float* wq = (const float*)d_in[1];
  const float* wk = (const float*)d_in[2];
  const float* wv = (const float*)d_in[3];
  const float* wo = (const float*)d_in[4];
  const float* bo = (const float*)d_in[5];
  float* out = (float*)d_out;

  u16* xb    = (u16*)d_ws;                      // 8M elems
  u16* wqkvb = xb + (size_t)8 * 1024 * 1024;    // 3M
  u16* wob   = wqkvb + (size_t)3 * 1024 * 1024; // 1M
  u16* qb    = wob + (size_t)1 * 1024 * 1024;   // 8M
  u16* kb    = qb + (size_t)8 * 1024 * 1024;    // 8M
  u16* vtb   = kb + (size_t)8 * 1024 * 1024;    // 8M (bit-swapped V^T)
  u16* ctxb  = xb;                              // alias: xb dead after gemm_qkv

  cvt_all<<<12288, 256, 0, stream>>>(x, wq, wk, wv, wo, xb, wqkvb, wob);
  gemm_qkv<<<64 * 24, 256, 0, stream>>>(xb, wqkvb, qb, kb, vtb);
  attn_kernel<<<1024, 256, 0, stream>>>(qb, kb, vtb, ctxb);
  gemm_out<<<64 * 8, 256, 0, stream>>>(ctxb, wob, bo, out);
}